// Round 9
// baseline (963.506 us; speedup 1.0000x reference)
//
#include <hip/hip_runtime.h>
#include <hip/hip_bf16.h>

#define NN    20000   // nodes
#define KE    16      // ego-net size
#define FIN   128     // input feats / hidden
#define FOUT2 64      // output classes
#define NE    640000  // edges
#define NB    79      // scan blocks: ceil(NN/256)
#define HBE   313     // bucket blocks: ceil(NE/8/256)
#define BE    100     // edge-hist blocks (LDS histogram)
#define CE    6400    // items per hist block (BE*CE=NE)
#define GB1   1250    // dense-GEMM blocks (16 rows each)
#define ZB    160     // zeroing blocks in mega
#define APAD  17      // padded row stride for A in LDS

// ---- bf16 helpers (ushort storage, fp32 math) ----
__device__ __forceinline__ float bf2f(unsigned short u) {
    union { float f; unsigned int i; } c; c.i = ((unsigned int)u) << 16; return c.f;
}
__device__ __forceinline__ unsigned short f2bf(float f) {
    union { float f; unsigned int i; } c; c.f = f;
    unsigned int lsb = (c.i >> 16) & 1u;
    c.i += 0x7fffu + lsb;           // round-to-nearest-even
    return (unsigned short)(c.i >> 16);
}
__device__ __forceinline__ float4 ldx4(const unsigned short* p, size_t i) {
    ushort4 u = *(const ushort4*)(p + i);
    float4 r; r.x = bf2f(u.x); r.y = bf2f(u.y); r.z = bf2f(u.z); r.w = bf2f(u.w);
    return r;
}
__device__ __forceinline__ float2 ldu2(const unsigned short* p, size_t i) {
    ushort2 u = *(const ushort2*)(p + i);
    float2 r; r.x = bf2f(u.x); r.y = bf2f(u.y); return r;
}
// HW fp32 atomic add (global_atomic_add_f32), no CAS loop
__device__ __forceinline__ void atomAddF(float* p, float v) { unsafeAtomicAdd(p, v); }

// ---- mega: edge LDS-hist [0,BE) || xW1 GEMM || Wc = We2@Wg2 || zero accums -
// hist: PACKED u16 LDS counters (2 per u32, 40 KB; max count 6400 so no carry
// across the 16-bit boundary). atomicAdd returns per-item rank -> posarr u16.
// Ego side needs NO CSR anymore (fp32-atomic aggregation) -> 50 hist blocks,
// 79 scan blocks, 320K bucket items and the 82 MB Y round-trip all deleted.
__global__ __launch_bounds__(256) void mega_kernel(
    const int* __restrict__ dst,
    unsigned short* __restrict__ counts_e, unsigned short* __restrict__ posarr,
    const float* __restrict__ x, const float* __restrict__ W1,
    unsigned short* __restrict__ xW1,
    const float* __restrict__ We2, const float* __restrict__ Wg2,
    const float* __restrict__ be2, float* __restrict__ Wc, float* __restrict__ bc,
    float* __restrict__ zeros) {         // rowsAcc||acc2, NN*(FIN+FOUT2) floats
    __shared__ unsigned int smem4[NN / 2];  // 40 KB, shared by hist & GEMM
    const int t = threadIdx.x;
    if (blockIdx.x < BE) {                  // ---- edge LDS histogram ----
        unsigned int* h32 = smem4;
        const int b = blockIdx.x;
        for (int k = t; k < NN / 2; k += 256) h32[k] = 0u;
        __syncthreads();
        const int base = b * CE;
#pragma unroll 5
        for (int it = 0; it < CE / 256; ++it) {
            const int i = base + it * 256 + t;
            const int key = dst[i];
            const int sh = (key & 1) << 4;
            const unsigned int old = atomicAdd(&h32[key >> 1], 1u << sh);
            posarr[i] = (unsigned short)((old >> sh) & 0xffffu);
        }
        __syncthreads();
        unsigned short* cnt = counts_e + b * NN;
        for (int k = t; k < NN / 2; k += 256)
            *(unsigned int*)(cnt + 2 * k) = h32[k];   // pair dump (aligned)
        return;
    }
    if (blockIdx.x < BE + GB1) {            // ---- GEMM: xW1 = x @ W1 -> bf16
        float (*rl)[FIN] = (float(*)[FIN])smem4;   // 8 KB of the 40 KB
        const int r0 = (blockIdx.x - BE) * 16;
        for (int idx = t; idx < 16 * FIN; idx += 256)
            rl[idx >> 7][idx & 127] = x[(size_t)(r0 + (idx >> 7)) * FIN + (idx & 127)];
        __syncthreads();
        const int j = t & 127, g = t >> 7;
        float acc[8] = {};
        for (int k = 0; k < FIN; k += 4) {
            const float w0 = W1[k * FIN + j],       w1 = W1[(k + 1) * FIN + j];
            const float w2 = W1[(k + 2) * FIN + j], w3 = W1[(k + 3) * FIN + j];
#pragma unroll
            for (int r = 0; r < 8; ++r) {
                float4 rv = *(const float4*)&rl[g * 8 + r][k];
                acc[r] += rv.x * w0 + rv.y * w1 + rv.z * w2 + rv.w * w3;
            }
        }
#pragma unroll
        for (int r = 0; r < 8; ++r)
            xW1[(size_t)(r0 + g * 8 + r) * FIN + j] = f2bf(acc[r]);
        return;
    }
    if (blockIdx.x < BE + GB1 + 33) {       // ---- Wc = We2@Wg2, bc = be2@Wg2
        const int wb = blockIdx.x - BE - GB1;
        if (wb < 32) {
            const int row = wb * 4 + (t >> 6);
            const int j = t & 63;
            float s = 0.f;
            for (int k = 0; k < FIN; ++k) s += We2[row * FIN + k] * Wg2[k * FOUT2 + j];
            Wc[row * FOUT2 + j] = s;
        } else if (t < FOUT2) {
            float s = 0.f;
            for (int k = 0; k < FIN; ++k) s += be2[k] * Wg2[k * FOUT2 + t];
            bc[t] = s;
        }
        return;
    }
    // ---- zero the fp32 accumulators (rowsAcc || acc2, contiguous) ----
    float4* z4 = (float4*)zeros;
    const int total4 = NN * (FIN + FOUT2) / 4;   // 960000 float4
    const int stride = ZB * 256;
    const float4 zz = {0.f, 0.f, 0.f, 0.f};
    for (int i = (blockIdx.x - BE - GB1 - 33) * 256 + t; i < total4; i += stride)
        z4[i] = zz;
}

// ---- scan p1 (edges only) || weight-combine stage 2 ------------------------
__global__ __launch_bounds__(256) void scan_p1_kernel(
    unsigned short* __restrict__ counts_e,
    int* __restrict__ scantmp, int* __restrict__ bsums, float* __restrict__ dinv,
    const float* __restrict__ Wg1, const float* __restrict__ bg1,
    const float* __restrict__ Wc, float* __restrict__ Wgc, float* __restrict__ bgc) {
    const int t = threadIdx.x;
    if (blockIdx.x >= NB) {                 // ---- Wgc = Wg1 @ Wc (parallel) --
        const int wb = blockIdx.x - NB;
        if (wb < 32) {
            const int row = wb * 4 + (t >> 6);
            const int j = t & 63;
            float s = 0.f;
            for (int k = 0; k < FIN; ++k) s += Wg1[row * FIN + k] * Wc[k * FOUT2 + j];
            Wgc[row * FOUT2 + j] = s;
        } else if (t < FOUT2) {
            float s = 0.f;
            for (int k = 0; k < FIN; ++k) s += bg1[k] * Wc[k * FOUT2 + t];
            bgc[t] = s;
        }
        return;
    }
    const int blk = blockIdx.x;
    const int k = blk * 256 + t;
    int run = 0;
    if (k < NN) {
        for (int b = 0; b < BE; b += 4) {          // 25 iters, 4 loads in flight
            const int i0 = b * NN + k;
            const int c0 = counts_e[i0],          c1 = counts_e[i0 + NN];
            const int c2 = counts_e[i0 + 2 * NN], c3 = counts_e[i0 + 3 * NN];
            counts_e[i0]          = (unsigned short)run; run += c0;
            counts_e[i0 + NN]     = (unsigned short)run; run += c1;
            counts_e[i0 + 2 * NN] = (unsigned short)run; run += c2;
            counts_e[i0 + 3 * NN] = (unsigned short)run; run += c3;
        }
        dinv[k] = rsqrtf((float)(run + 1));        // +1 self loop
    }
    __shared__ int sh[256];
    sh[t] = run;
    __syncthreads();
    for (int o = 1; o < 256; o <<= 1) {
        int u = (t >= o) ? sh[t - o] : 0;
        __syncthreads();
        sh[t] += u;
        __syncthreads();
    }
    if (k < NN) scantmp[k] = sh[t] - run;          // exclusive within block
    if (t == 255) bsums[blk] = sh[255];
}

// ---- bucket (edges only, scan_p3 folded): every block LDS-scans bsums ------
__global__ void bucket_e_kernel(const int* __restrict__ src, const int* __restrict__ dst,
                                const int* __restrict__ scantmp, const int* __restrict__ bsums,
                                const unsigned short* __restrict__ counts_e,
                                const unsigned short* __restrict__ posarr,
                                int* __restrict__ csr_src, int* __restrict__ rowstart) {
    __shared__ int pref[256];       // inclusive scan of the 79 block sums
    const int t = threadIdx.x;
    pref[t] = (t < NB) ? bsums[t] : 0;
    __syncthreads();
    for (int o = 1; o < 256; o <<= 1) {
        int u = (t >= o) ? pref[t - o] : 0;
        __syncthreads();
        pref[t] += u;
        __syncthreads();
    }
    if (blockIdx.x < NB) {          // materialize rowstart
        const int i = blockIdx.x * 256 + t;
        if (i < NN) {
            const int ofs = (blockIdx.x == 0) ? 0 : pref[blockIdx.x - 1];
            rowstart[i] = scantmp[i] + ofs;
        }
        if (blockIdx.x == 0 && t == 0) rowstart[NN] = NE;
    }
    const int base = blockIdx.x * 2048 + t;
#pragma unroll
    for (int q = 0; q < 8; ++q) {
        const int i = base + q * 256;
        if (i < NE) {
            const int key = dst[i];
            const int b = i / CE;
            const int kb = key >> 8;
            const int ofs = (kb == 0) ? 0 : pref[kb - 1];
            csr_src[scantmp[key] + ofs + (int)counts_e[b * NN + key] + (int)posarr[i]] = src[i];
        }
    }
}

// ---- ego apply (128-wide): rowsAcc[ids[n][i]] += ((A@A) @ xW1[ids[n]])[i] --
// fp32 HW atomics into the dense accumulator; no Y materialization.
__global__ __launch_bounds__(256) void ego_apply_kernel(
    const unsigned short* __restrict__ x, const int* __restrict__ ego_ids,
    const float* __restrict__ ego_adj, float* __restrict__ rowsAcc) {
    __shared__ float Ar[8][KE * APAD];
    __shared__ float As[8][256];
    __shared__ int ids[8][KE];
    const int w = threadIdx.x >> 5;
    const int c = threadIdx.x & 31;
    const int n = blockIdx.x * 8 + w;
    const float* a = ego_adj + (size_t)n * 256;
#pragma unroll
    for (int e = 0; e < 8; ++e) {
        const int idx = c * 8 + e;
        Ar[w][(idx >> 4) * APAD + (idx & 15)] = a[idx];
    }
    if (c < KE) ids[w][c] = ego_ids[n * KE + c];
    __syncthreads();
    {
        const int i = c >> 1;
        const int k0 = (c & 1) * 8;
        float s[8] = {};
#pragma unroll
        for (int j = 0; j < KE; ++j) {
            const float aij = Ar[w][i * APAD + j];
            const float* arow = &Ar[w][j * APAD + k0];
#pragma unroll
            for (int q = 0; q < 8; ++q) s[q] += aij * arow[q];
        }
        float4 s0 = {s[0], s[1], s[2], s[3]}, s1 = {s[4], s[5], s[6], s[7]};
        *(float4*)&As[w][i * 16 + k0]     = s0;
        *(float4*)&As[w][i * 16 + k0 + 4] = s1;
    }
    __syncthreads();
    float4 xg[KE];
#pragma unroll
    for (int k = 0; k < KE; ++k) xg[k] = ldx4(x, (size_t)ids[w][k] * FIN + 4 * c);
#pragma unroll
    for (int i = 0; i < KE; ++i) {
        float4 acc = {0.f, 0.f, 0.f, 0.f};
#pragma unroll
        for (int k = 0; k < KE; ++k) {
            const float a2 = As[w][i * 16 + k];
            acc.x += a2 * xg[k].x; acc.y += a2 * xg[k].y;
            acc.z += a2 * xg[k].z; acc.w += a2 * xg[k].w;
        }
        float* dstp = rowsAcc + (size_t)ids[w][i] * FIN + 4 * c;
        atomAddF(dstp + 0, acc.x); atomAddF(dstp + 1, acc.y);
        atomAddF(dstp + 2, acc.z); atomAddF(dstp + 3, acc.w);
    }
}

// ---- dual1: rows = relu(ndeg*rowsAcc + b1); mC = (rows @ Wgc)*dinv -> bf16 -
__global__ __launch_bounds__(256) void dual1_kernel(
    const float* __restrict__ rowsAcc,
    const float* __restrict__ ndeg, const float* __restrict__ b1,
    const float* __restrict__ Wgc, const float* __restrict__ dinv,
    unsigned short* __restrict__ mC) {
    constexpr int ROWS = 8;
    const int r0 = blockIdx.x * ROWS;
    const int t = threadIdx.x;
    __shared__ float rows[ROWS][FIN];
    {
        const int w = t >> 6;           // wave 0..3
        const int l = t & 63;           // lane owns features 2l, 2l+1
#pragma unroll
        for (int rr = 0; rr < ROWS; rr += 4) {
            const int r = rr + w;
            const int v = r0 + r;
            const float2 a = *(const float2*)&rowsAcc[(size_t)v * FIN + 2 * l];
            const float nd = ndeg[v];
            const float2 bb = *(const float2*)&b1[2 * l];
            rows[r][2 * l]     = fmaxf(a.x * nd + bb.x, 0.f);
            rows[r][2 * l + 1] = fmaxf(a.y * nd + bb.y, 0.f);
        }
    }
    __syncthreads();
    {
        const int j = t & 63;
        const int g = t >> 6;           // 4 groups x 2 rows
        float acc[2] = {};
        for (int k = 0; k < FIN; k += 4) {
            const float w0 = Wgc[k * FOUT2 + j],       w1 = Wgc[(k + 1) * FOUT2 + j];
            const float w2 = Wgc[(k + 2) * FOUT2 + j], w3 = Wgc[(k + 3) * FOUT2 + j];
#pragma unroll
            for (int r = 0; r < 2; ++r) {
                float4 rv = *(const float4*)&rows[g * 2 + r][k];
                acc[r] += rv.x * w0 + rv.y * w1 + rv.z * w2 + rv.w * w3;
            }
        }
#pragma unroll
        for (int r = 0; r < 2; ++r) {
            const int v = r0 + g * 2 + r;
            mC[(size_t)v * FOUT2 + j] = f2bf(acc[r] * dinv[v]);
        }
    }
}

// ------- GCN-1 gather, 64-wide, wave-per-node, 8 gathers in flight ----------
__global__ __launch_bounds__(256) void gcn2_gather64_kernel(
    const unsigned short* __restrict__ mC, const int* __restrict__ rowstart,
    const int* __restrict__ csr_src, const float* __restrict__ dinv,
    const float* __restrict__ bgc, unsigned short* __restrict__ hW2) {
    const int tid = threadIdx.x;
    const int d = blockIdx.x * 4 + (tid >> 6);
    const int t = tid & 63;
    float acc = bf2f(mC[(size_t)d * FOUT2 + t]);   // self loop
    int e = rowstart[d];
    const int eend = rowstart[d + 1];
    for (; e + 8 <= eend; e += 8) {
        const int s0 = csr_src[e],     s1 = csr_src[e + 1];
        const int s2 = csr_src[e + 2], s3 = csr_src[e + 3];
        const int s4 = csr_src[e + 4], s5 = csr_src[e + 5];
        const int s6 = csr_src[e + 6], s7 = csr_src[e + 7];
        const float v0 = bf2f(mC[(size_t)s0 * FOUT2 + t]);
        const float v1 = bf2f(mC[(size_t)s1 * FOUT2 + t]);
        const float v2 = bf2f(mC[(size_t)s2 * FOUT2 + t]);
        const float v3 = bf2f(mC[(size_t)s3 * FOUT2 + t]);
        const float v4 = bf2f(mC[(size_t)s4 * FOUT2 + t]);
        const float v5 = bf2f(mC[(size_t)s5 * FOUT2 + t]);
        const float v6 = bf2f(mC[(size_t)s6 * FOUT2 + t]);
        const float v7 = bf2f(mC[(size_t)s7 * FOUT2 + t]);
        acc += ((v0 + v1) + (v2 + v3)) + ((v4 + v5) + (v6 + v7));
    }
    for (; e < eend; ++e) acc += bf2f(mC[(size_t)csr_src[e] * FOUT2 + t]);
    hW2[(size_t)d * FOUT2 + t] = f2bf(acc * dinv[d] + bgc[t]);
}

// ---- ego apply (64-wide): acc2[ids[n][i]] += ((A@A) @ hW2[ids[n]])[i] ------
__global__ __launch_bounds__(256) void apply2_kernel(
    const unsigned short* __restrict__ hW2, const int* __restrict__ ego_ids,
    const float* __restrict__ ego_adj, float* __restrict__ acc2) {
    __shared__ float Ar[8][KE * APAD];
    __shared__ float As[8][256];
    __shared__ int ids[8][KE];
    const int w = threadIdx.x >> 5;
    const int c = threadIdx.x & 31;
    const int n = blockIdx.x * 8 + w;
    const float* a = ego_adj + (size_t)n * 256;
#pragma unroll
    for (int e = 0; e < 8; ++e) {
        const int idx = c * 8 + e;
        Ar[w][(idx >> 4) * APAD + (idx & 15)] = a[idx];
    }
    if (c < KE) ids[w][c] = ego_ids[n * KE + c];
    __syncthreads();
    {
        const int i = c >> 1;
        const int k0 = (c & 1) * 8;
        float s[8] = {};
#pragma unroll
        for (int j = 0; j < KE; ++j) {
            const float aij = Ar[w][i * APAD + j];
            const float* arow = &Ar[w][j * APAD + k0];
#pragma unroll
            for (int q = 0; q < 8; ++q) s[q] += aij * arow[q];
        }
        float4 s0 = {s[0], s[1], s[2], s[3]}, s1 = {s[4], s[5], s[6], s[7]};
        *(float4*)&As[w][i * 16 + k0]     = s0;
        *(float4*)&As[w][i * 16 + k0 + 4] = s1;
    }
    __syncthreads();
    float2 xg[KE];
#pragma unroll
    for (int k = 0; k < KE; ++k) xg[k] = ldu2(hW2, (size_t)ids[w][k] * FOUT2 + 2 * c);
#pragma unroll
    for (int i = 0; i < KE; ++i) {
        float sx = 0.f, sy = 0.f;
#pragma unroll
        for (int k = 0; k < KE; ++k) {
            const float a2 = As[w][i * 16 + k];
            sx += a2 * xg[k].x; sy += a2 * xg[k].y;
        }
        float* dstp = acc2 + (size_t)ids[w][i] * FOUT2 + 2 * c;
        atomAddF(dstp + 0, sx); atomAddF(dstp + 1, sy);
    }
}

// ---- dual2 (matmul-free): m2 = ((ndeg*acc2) + b_combo)*dinv -> bf16 --------
__global__ __launch_bounds__(256) void dual2_kernel(
    const float* __restrict__ acc2,
    const float* __restrict__ ndeg, const float* __restrict__ bc,
    const float* __restrict__ dinv, unsigned short* __restrict__ m2) {
    const int tid = threadIdx.x;
    const int d = blockIdx.x * 4 + (tid >> 6);
    const int t = tid & 63;
    const float acc = acc2[(size_t)d * FOUT2 + t];
    m2[(size_t)d * FOUT2 + t] = f2bf((acc * ndeg[d] + bc[t]) * dinv[d]);
}

// ------- fused GCN gather (F=64) + bias + log_softmax -> fp32, 8-deep -------
__global__ __launch_bounds__(256) void gcn_gather_lsm_kernel(
    const unsigned short* __restrict__ msg, const int* __restrict__ rowstart,
    const int* __restrict__ csr_src, const float* __restrict__ dinv,
    const float* __restrict__ b, float* __restrict__ out) {
    const int tid = threadIdx.x;
    const int d = blockIdx.x * 4 + (tid >> 6);
    const int t = tid & 63;
    float s = bf2f(msg[(size_t)d * FOUT2 + t]);  // self loop
    int e = rowstart[d];
    const int eend = rowstart[d + 1];
    for (; e + 8 <= eend; e += 8) {
        const int s0 = csr_src[e],     s1 = csr_src[e + 1];
        const int s2 = csr_src[e + 2], s3 = csr_src[e + 3];
        const int s4 = csr_src[e + 4], s5 = csr_src[e + 5];
        const int s6 = csr_src[e + 6], s7 = csr_src[e + 7];
        const float v0 = bf2f(msg[(size_t)s0 * FOUT2 + t]);
        const float v1 = bf2f(msg[(size_t)s1 * FOUT2 + t]);
        const float v2 = bf2f(msg[(size_t)s2 * FOUT2 + t]);
        const float v3 = bf2f(msg[(size_t)s3 * FOUT2 + t]);
        const float v4 = bf2f(msg[(size_t)s4 * FOUT2 + t]);
        const float v5 = bf2f(msg[(size_t)s5 * FOUT2 + t]);
        const float v6 = bf2f(msg[(size_t)s6 * FOUT2 + t]);
        const float v7 = bf2f(msg[(size_t)s7 * FOUT2 + t]);
        s += ((v0 + v1) + (v2 + v3)) + ((v4 + v5) + (v6 + v7));
    }
    for (; e < eend; ++e) s += bf2f(msg[(size_t)csr_src[e] * FOUT2 + t]);
    const float xv = s * dinv[d] + b[t];
    float m = xv;
#pragma unroll
    for (int o = 32; o > 0; o >>= 1) m = fmaxf(m, __shfl_xor(m, o));
    float ex = __expf(xv - m);
    float sm = ex;
#pragma unroll
    for (int o = 32; o > 0; o >>= 1) sm += __shfl_xor(sm, o);
    out[(size_t)d * FOUT2 + t] = xv - m - __logf(sm);
}

extern "C" void kernel_launch(void* const* d_in, const int* in_sizes, int n_in,
                              void* d_out, int out_size, void* d_ws, size_t ws_size,
                              hipStream_t stream) {
    (void)in_sizes; (void)n_in; (void)out_size; (void)ws_size;
    const float* x      = (const float*)d_in[0];
    const int*   eidx   = (const int*)d_in[1];
    const int*   egoids = (const int*)d_in[2];
    const float* egoadj = (const float*)d_in[3];
    const float* ndeg   = (const float*)d_in[4];
    const float* W_ego1 = (const float*)d_in[5];
    const float* b_ego1 = (const float*)d_in[6];
    const float* W_gcn1 = (const float*)d_in[7];
    const float* b_gcn1 = (const float*)d_in[8];
    const float* W_ego2 = (const float*)d_in[9];
    const float* b_ego2 = (const float*)d_in[10];
    const float* W_gcn2 = (const float*)d_in[11];
    const float* b_gcn2 = (const float*)d_in[12];
    const int* src = eidx;
    const int* dst = eidx + NE;

    // ---- workspace layout (~35 MB) ----
    int* ip = (int*)d_ws;
    int* rowstart  = ip;                    // NN+1 (+pad)
    int* csr_src   = rowstart + NN + 8;     // NE
    int* scantmp   = csr_src + NE;          // NN
    int* bsums     = scantmp + NN;          // NB (+pad)
    unsigned short* counts_e = (unsigned short*)(bsums + 128);  // BE*NN u16
    unsigned short* posarr   = counts_e + BE * NN;              // NE u16
    float* dinv = (float*)(posarr + NE);                // NN
    float* Wc   = dinv + NN;                            // 128*64 fp32 (stage 1)
    float* Wgc  = Wc + FIN * FOUT2;                     // 128*64 fp32 (stage 2)
    float* bc   = Wgc + FIN * FOUT2;                    // 64
    float* bgc  = bc + 64;                              // 64
    unsigned short* xW1 = (unsigned short*)(bgc + 64);   // NN*128 bf16
    unsigned short* mC  = xW1 + (size_t)NN * FIN;        // NN*64 bf16 (GCN-1 msg)
    unsigned short* hW2 = mC + (size_t)NN * FOUT2;       // NN*64 bf16
    unsigned short* m2  = hW2 + (size_t)NN * FOUT2;      // NN*64 bf16 msgs L2
    // fp32 accumulators, contiguous for one-shot zeroing (aligned: all prior
    // u16 regions have even element counts)
    float* rowsAcc = (float*)(m2 + (size_t)NN * FOUT2);  // NN*128 fp32
    float* acc2    = rowsAcc + (size_t)NN * FIN;         // NN*64  fp32

    // ---- edge CSR build || xW1 GEMM || Wc || zero accums ----
    mega_kernel<<<BE + GB1 + 33 + ZB, 256, 0, stream>>>(dst, counts_e, posarr,
                                                        x, W_ego1, xW1,
                                                        W_ego2, W_gcn2, b_ego2,
                                                        Wc, bc, rowsAcc);
    // ---- edge plane scan || Wgc = Wg1@Wc ----
    scan_p1_kernel<<<NB + 33, 256, 0, stream>>>(counts_e, scantmp, bsums, dinv,
                                                W_gcn1, b_gcn1, Wc, Wgc, bgc);
    // ---- edge bucket (p3 folded) ----
    bucket_e_kernel<<<HBE, 256, 0, stream>>>(src, dst, scantmp, bsums,
                                             counts_e, posarr, csr_src, rowstart);

    // ---- layer 1 (ego aggregation via fp32 atomics) ----
    ego_apply_kernel<<<NN / 8, 256, 0, stream>>>(xW1, egoids, egoadj, rowsAcc);
    dual1_kernel<<<NN / 8, 256, 0, stream>>>(rowsAcc, ndeg, b_ego1, Wgc, dinv, mC);
    gcn2_gather64_kernel<<<NN / 4, 256, 0, stream>>>(mC, rowstart, csr_src, dinv, bgc, hW2);

    // ---- layer 2 ----
    apply2_kernel<<<NN / 8, 256, 0, stream>>>(hW2, egoids, egoadj, acc2);
    dual2_kernel<<<NN / 4, 256, 0, stream>>>(acc2, ndeg, bc, dinv, m2);
    gcn_gather_lsm_kernel<<<NN / 4, 256, 0, stream>>>(m2, rowstart, csr_src, dinv, b_gcn2, (float*)d_out);
}

// Round 10
// 271.029 us; speedup vs baseline: 3.5550x; 3.5550x over previous
//
#include <hip/hip_runtime.h>
#include <hip/hip_bf16.h>

#define NN    20000   // nodes
#define KE    16      // ego-net size
#define FIN   128     // input feats / hidden
#define FOUT2 64      // output classes
#define NE    640000  // edges
#define NB    79      // scan blocks per array: ceil(NN/256)
#define TOT   (NE + NN * KE)        // 960000 items
#define HB    469                   // bucket blocks: ceil(TOT/8/256)
#define BE    100     // edge-hist blocks (LDS histogram)
#define BG    50      // ego-hist blocks
#define CE    6400    // items per hist block (BE*CE=NE, BG*CE=NN*KE)
#define GB1   1250    // dense-GEMM blocks (16 rows each)
#define APAD  17      // padded row stride for A in LDS

// ---- bf16 helpers (ushort storage, fp32 math) ----
__device__ __forceinline__ float bf2f(unsigned short u) {
    union { float f; unsigned int i; } c; c.i = ((unsigned int)u) << 16; return c.f;
}
__device__ __forceinline__ unsigned short f2bf(float f) {
    union { float f; unsigned int i; } c; c.f = f;
    unsigned int lsb = (c.i >> 16) & 1u;
    c.i += 0x7fffu + lsb;           // round-to-nearest-even
    return (unsigned short)(c.i >> 16);
}
__device__ __forceinline__ float4 ldx4(const unsigned short* p, size_t i) {
    ushort4 u = *(const ushort4*)(p + i);
    float4 r; r.x = bf2f(u.x); r.y = bf2f(u.y); r.z = bf2f(u.z); r.w = bf2f(u.w);
    return r;
}
__device__ __forceinline__ float2 ldu2(const unsigned short* p, size_t i) {
    ushort2 u = *(const ushort2*)(p + i);
    float2 r; r.x = bf2f(u.x); r.y = bf2f(u.y); return r;
}

// ---- mega: LDS-hist [0,BE+BG) || xW1 GEMM || Wc = We2@Wg2 (parallel) -------
// hist: PACKED u16 LDS counters (2 per u32, 40 KB; max count 6400 so no carry
// across the 16-bit boundary). atomicAdd returns per-item rank -> posarr u16.
// NOTE (round-9 lesson): fp32 global-atomic aggregation for the ego side was
// tested and REFUTED -- 41M unsafeAtomicAdd produced 640 MB of HBM RMW
// traffic (604 us). The CSR scatter below is the right structure on MI355X.
__global__ __launch_bounds__(256) void mega_kernel(
    const int* __restrict__ dst, const int* __restrict__ ego_flat,
    unsigned short* __restrict__ counts_e, unsigned short* __restrict__ counts_g,
    unsigned short* __restrict__ posarr,
    const float* __restrict__ x, const float* __restrict__ W1,
    unsigned short* __restrict__ xW1,
    const float* __restrict__ We2, const float* __restrict__ Wg2,
    const float* __restrict__ be2, float* __restrict__ Wc, float* __restrict__ bc) {
    __shared__ unsigned int smem4[NN / 2];  // 40 KB, shared by hist & GEMM
    const int t = threadIdx.x;
    if (blockIdx.x < BE + BG) {             // ---- LDS histogram part ----
        unsigned int* h32 = smem4;
        const bool isE = blockIdx.x < BE;
        const int b = isE ? blockIdx.x : blockIdx.x - BE;
        for (int k = t; k < NN / 2; k += 256) h32[k] = 0u;
        __syncthreads();
        const int base = b * CE;
#pragma unroll 5
        for (int it = 0; it < CE / 256; ++it) {
            const int i = base + it * 256 + t;
            const int key = isE ? dst[i] : ego_flat[i];
            const int sh = (key & 1) << 4;
            const unsigned int old = atomicAdd(&h32[key >> 1], 1u << sh);
            posarr[isE ? i : NE + i] = (unsigned short)((old >> sh) & 0xffffu);
        }
        __syncthreads();
        unsigned short* cnt = isE ? (counts_e + b * NN) : (counts_g + b * NN);
        for (int k = t; k < NN / 2; k += 256)
            *(unsigned int*)(cnt + 2 * k) = h32[k];   // pair dump (aligned)
        return;
    }
    if (blockIdx.x < BE + BG + GB1) {       // ---- GEMM: xW1 = x @ W1 -> bf16
        float (*rl)[FIN] = (float(*)[FIN])smem4;   // 8 KB of the 40 KB
        const int r0 = (blockIdx.x - BE - BG) * 16;
        for (int idx = t; idx < 16 * FIN; idx += 256)
            rl[idx >> 7][idx & 127] = x[(size_t)(r0 + (idx >> 7)) * FIN + (idx & 127)];
        __syncthreads();
        const int j = t & 127, g = t >> 7;
        float acc[8] = {};
        for (int k = 0; k < FIN; k += 4) {
            const float w0 = W1[k * FIN + j],       w1 = W1[(k + 1) * FIN + j];
            const float w2 = W1[(k + 2) * FIN + j], w3 = W1[(k + 3) * FIN + j];
#pragma unroll
            for (int r = 0; r < 8; ++r) {
                float4 rv = *(const float4*)&rl[g * 8 + r][k];
                acc[r] += rv.x * w0 + rv.y * w1 + rv.z * w2 + rv.w * w3;
            }
        }
#pragma unroll
        for (int r = 0; r < 8; ++r)
            xW1[(size_t)(r0 + g * 8 + r) * FIN + j] = f2bf(acc[r]);
        return;
    }
    // ---- Wc = W_ego2 @ W_gcn2 (128x64), bc = b_ego2 @ W_gcn2 (parallel) ----
    const int wb = blockIdx.x - BE - BG - GB1;
    if (wb < 32) {
        const int row = wb * 4 + (t >> 6);
        const int j = t & 63;
        float s = 0.f;
        for (int k = 0; k < FIN; ++k) s += We2[row * FIN + k] * Wg2[k * FOUT2 + j];
        Wc[row * FOUT2 + j] = s;
    } else if (t < FOUT2) {
        float s = 0.f;
        for (int k = 0; k < FIN; ++k) s += be2[k] * Wg2[k * FOUT2 + t];
        bc[t] = s;
    }
}

// ---- scan p1 (+folded column-scan) || weight-combine stage 2 ---------------
// Extra 33 blocks: Wgc = W_gcn1 @ Wc, bgc = b_gcn1 @ Wc (Wc ready: mega done).
__global__ __launch_bounds__(256) void scan_p1_kernel(
    unsigned short* __restrict__ counts_e, unsigned short* __restrict__ counts_g,
    int* __restrict__ scantmp, int* __restrict__ bsums, float* __restrict__ dinv,
    const float* __restrict__ Wg1, const float* __restrict__ bg1,
    const float* __restrict__ Wc, float* __restrict__ Wgc, float* __restrict__ bgc) {
    const int t = threadIdx.x;
    if (blockIdx.x >= 2 * NB) {             // ---- Wgc = Wg1 @ Wc (parallel) --
        const int wb = blockIdx.x - 2 * NB;
        if (wb < 32) {
            const int row = wb * 4 + (t >> 6);
            const int j = t & 63;
            float s = 0.f;
            for (int k = 0; k < FIN; ++k) s += Wg1[row * FIN + k] * Wc[k * FOUT2 + j];
            Wgc[row * FOUT2 + j] = s;
        } else if (t < FOUT2) {
            float s = 0.f;
            for (int k = 0; k < FIN; ++k) s += bg1[k] * Wc[k * FOUT2 + t];
            bgc[t] = s;
        }
        return;
    }
    const int arr = (blockIdx.x >= NB) ? 1 : 0;
    const int blk = blockIdx.x - arr * NB;
    const int k = blk * 256 + t;
    int run = 0;
    if (k < NN) {
        if (arr == 0) {
            for (int b = 0; b < BE; b += 4) {          // 25 iters, 4 loads in flight
                const int i0 = b * NN + k;
                const int c0 = counts_e[i0],          c1 = counts_e[i0 + NN];
                const int c2 = counts_e[i0 + 2 * NN], c3 = counts_e[i0 + 3 * NN];
                counts_e[i0]          = (unsigned short)run; run += c0;
                counts_e[i0 + NN]     = (unsigned short)run; run += c1;
                counts_e[i0 + 2 * NN] = (unsigned short)run; run += c2;
                counts_e[i0 + 3 * NN] = (unsigned short)run; run += c3;
            }
            dinv[k] = rsqrtf((float)(run + 1));        // +1 self loop
        } else {
            for (int b = 0; b < BG; b += 5) {          // 10 iters, 5 loads in flight
                const int i0 = b * NN + k;
                const int c0 = counts_g[i0],          c1 = counts_g[i0 + NN];
                const int c2 = counts_g[i0 + 2 * NN], c3 = counts_g[i0 + 3 * NN];
                const int c4 = counts_g[i0 + 4 * NN];
                counts_g[i0]          = (unsigned short)run; run += c0;
                counts_g[i0 + NN]     = (unsigned short)run; run += c1;
                counts_g[i0 + 2 * NN] = (unsigned short)run; run += c2;
                counts_g[i0 + 3 * NN] = (unsigned short)run; run += c3;
                counts_g[i0 + 4 * NN] = (unsigned short)run; run += c4;
            }
        }
    }
    __shared__ int sh[256];
    sh[t] = run;
    __syncthreads();
    for (int o = 1; o < 256; o <<= 1) {
        int u = (t >= o) ? sh[t - o] : 0;
        __syncthreads();
        sh[t] += u;
        __syncthreads();
    }
    if (k < NN) scantmp[arr * NN + k] = sh[t] - run;  // exclusive within block
    if (t == 255) bsums[arr * NB + blk] = sh[255];
}

// ---- bucket (scan_p3 folded in): every block LDS-scans the 2x79 bsums and
// scatters via scantmp[key]+pref on the fly; first 158 blocks also
// materialize rowstart/erowstart for the downstream kernels.
__global__ void bucket3_kernel(const int* __restrict__ src, const int* __restrict__ dst,
                               const int* __restrict__ ego_flat,
                               const int* __restrict__ scantmp, const int* __restrict__ bsums,
                               const unsigned short* __restrict__ counts_e,
                               const unsigned short* __restrict__ counts_g,
                               const unsigned short* __restrict__ posarr,
                               int* __restrict__ csr_src, int* __restrict__ yslot,
                               int* __restrict__ rowstart, int* __restrict__ erowstart) {
    __shared__ int pref[256];       // [0..78] arr0 inclusive, [128..206] arr1
    const int t = threadIdx.x;
    const int half = t >> 7, idx = t & 127;
    pref[t] = (idx < NB) ? bsums[half * NB + idx] : 0;
    __syncthreads();
    for (int o = 1; o < 128; o <<= 1) {
        int u = (idx >= o) ? pref[t - o] : 0;
        __syncthreads();
        pref[t] += u;
        __syncthreads();
    }
    // materialize rowstart/erowstart (first 158 blocks)
    if (blockIdx.x < 2 * NB) {
        const int arr = (blockIdx.x >= NB) ? 1 : 0;
        const int blk = blockIdx.x - arr * NB;
        const int i = blk * 256 + t;
        if (i < NN) {
            const int ofs = (blk == 0) ? 0 : pref[arr * 128 + blk - 1];
            const int val = scantmp[arr * NN + i] + ofs;
            if (arr) erowstart[i] = val; else rowstart[i] = val;
        }
        if (blockIdx.x == 0 && t == 0) { rowstart[NN] = NE; erowstart[NN] = NN * KE; }
    }
    // scatter
    const int base = blockIdx.x * 2048 + t;
#pragma unroll
    for (int q = 0; q < 8; ++q) {
        const int i = base + q * 256;
        if (i < TOT) {
            if (i < NE) {
                const int key = dst[i];
                const int b = i / CE;
                const int kb = key >> 8;
                const int ofs = (kb == 0) ? 0 : pref[kb - 1];
                csr_src[scantmp[key] + ofs + (int)counts_e[b * NN + key] + (int)posarr[i]] = src[i];
            } else {
                const int p = i - NE;
                const int key = ego_flat[p];
                const int b = p / CE;
                const int kb = key >> 8;
                const int ofs = (kb == 0) ? 0 : pref[128 + kb - 1];
                yslot[p] = scantmp[NN + key] + ofs + (int)counts_g[b * NN + key] + (int)posarr[i];
            }
        }
    }
}

// ---- ego apply (128-wide): Y[yslot[n,i]] = ((A@A) @ xW1[ids[n]])[i] --------
__global__ __launch_bounds__(256) void ego_apply_kernel(
    const unsigned short* __restrict__ x, const int* __restrict__ ego_ids,
    const float* __restrict__ ego_adj, const int* __restrict__ yslot,
    unsigned short* __restrict__ Y) {
    __shared__ float Ar[8][KE * APAD];
    __shared__ float As[8][256];
    __shared__ int ids[8][KE];
    __shared__ int slots[8][KE];
    const int w = threadIdx.x >> 5;
    const int c = threadIdx.x & 31;
    const int n = blockIdx.x * 8 + w;
    const float* a = ego_adj + (size_t)n * 256;
#pragma unroll
    for (int e = 0; e < 8; ++e) {
        const int idx = c * 8 + e;
        Ar[w][(idx >> 4) * APAD + (idx & 15)] = a[idx];
    }
    if (c < KE) {
        ids[w][c] = ego_ids[n * KE + c];
        slots[w][c] = yslot[n * KE + c];
    }
    __syncthreads();
    {
        const int i = c >> 1;
        const int k0 = (c & 1) * 8;
        float s[8] = {};
#pragma unroll
        for (int j = 0; j < KE; ++j) {
            const float aij = Ar[w][i * APAD + j];
            const float* arow = &Ar[w][j * APAD + k0];
#pragma unroll
            for (int q = 0; q < 8; ++q) s[q] += aij * arow[q];
        }
        float4 s0 = {s[0], s[1], s[2], s[3]}, s1 = {s[4], s[5], s[6], s[7]};
        *(float4*)&As[w][i * 16 + k0]     = s0;
        *(float4*)&As[w][i * 16 + k0 + 4] = s1;
    }
    __syncthreads();
    float4 xg[KE];
#pragma unroll
    for (int k = 0; k < KE; ++k) xg[k] = ldx4(x, (size_t)ids[w][k] * FIN + 4 * c);
#pragma unroll
    for (int i = 0; i < KE; ++i) {
        float4 acc = {0.f, 0.f, 0.f, 0.f};
#pragma unroll
        for (int k = 0; k < KE; ++k) {
            const float a2 = As[w][i * 16 + k];
            acc.x += a2 * xg[k].x; acc.y += a2 * xg[k].y;
            acc.z += a2 * xg[k].z; acc.w += a2 * xg[k].w;
        }
        ushort4 o; o.x = f2bf(acc.x); o.y = f2bf(acc.y);
        o.z = f2bf(acc.z); o.w = f2bf(acc.w);
        *(ushort4*)(Y + (size_t)slots[w][i] * FIN + 4 * c) = o;
    }
}

// ---- dual1: rows = relu(ndeg*sumY + b1); mC = (rows @ Wgc)*dinv -> bf16 ----
// Full wave covers the 128-wide row with ushort2/lane: no shuffles, 8-deep.
__global__ __launch_bounds__(256) void dual1_kernel(
    const unsigned short* __restrict__ Y, const int* __restrict__ erowstart,
    const float* __restrict__ ndeg, const float* __restrict__ b1,
    const float* __restrict__ Wgc, const float* __restrict__ dinv,
    unsigned short* __restrict__ mC) {
    constexpr int ROWS = 8;
    const int r0 = blockIdx.x * ROWS;
    const int t = threadIdx.x;
    __shared__ float rows[ROWS][FIN];
    {
        const int w = t >> 6;           // wave 0..3
        const int l = t & 63;           // lane owns features 2l, 2l+1
        for (int rr = 0; rr < ROWS; rr += 4) {
            const int r = rr + w;
            const int v = r0 + r;
            float ax = 0.f, ay = 0.f;
            int s = erowstart[v];
            const int send = erowstart[v + 1];
            for (; s + 8 <= send; s += 8) {     // 8 rows in flight
                float2 a0 = ldu2(Y, (size_t)s * FIN + 2 * l);
                float2 a1 = ldu2(Y, (size_t)(s + 1) * FIN + 2 * l);
                float2 a2 = ldu2(Y, (size_t)(s + 2) * FIN + 2 * l);
                float2 a3 = ldu2(Y, (size_t)(s + 3) * FIN + 2 * l);
                float2 a4 = ldu2(Y, (size_t)(s + 4) * FIN + 2 * l);
                float2 a5 = ldu2(Y, (size_t)(s + 5) * FIN + 2 * l);
                float2 a6 = ldu2(Y, (size_t)(s + 6) * FIN + 2 * l);
                float2 a7 = ldu2(Y, (size_t)(s + 7) * FIN + 2 * l);
                ax += ((a0.x + a1.x) + (a2.x + a3.x)) + ((a4.x + a5.x) + (a6.x + a7.x));
                ay += ((a0.y + a1.y) + (a2.y + a3.y)) + ((a4.y + a5.y) + (a6.y + a7.y));
            }
            for (; s < send; ++s) {
                float2 a = ldu2(Y, (size_t)s * FIN + 2 * l);
                ax += a.x; ay += a.y;
            }
            const float nd = ndeg[v];
            const float2 bb = *(const float2*)&b1[2 * l];
            rows[r][2 * l]     = fmaxf(ax * nd + bb.x, 0.f);
            rows[r][2 * l + 1] = fmaxf(ay * nd + bb.y, 0.f);
        }
    }
    __syncthreads();
    {
        const int j = t & 63;
        const int g = t >> 6;           // 4 groups x 2 rows
        float acc[2] = {};
        for (int k = 0; k < FIN; k += 4) {
            const float w0 = Wgc[k * FOUT2 + j],       w1 = Wgc[(k + 1) * FOUT2 + j];
            const float w2 = Wgc[(k + 2) * FOUT2 + j], w3 = Wgc[(k + 3) * FOUT2 + j];
#pragma unroll
            for (int r = 0; r < 2; ++r) {
                float4 rv = *(const float4*)&rows[g * 2 + r][k];
                acc[r] += rv.x * w0 + rv.y * w1 + rv.z * w2 + rv.w * w3;
            }
        }
#pragma unroll
        for (int r = 0; r < 2; ++r) {
            const int v = r0 + g * 2 + r;
            mC[(size_t)v * FOUT2 + j] = f2bf(acc[r] * dinv[v]);
        }
    }
}

// ------- GCN-1 gather, 64-wide, wave-per-node, 8 gathers in flight ----------
__global__ __launch_bounds__(256) void gcn2_gather64_kernel(
    const unsigned short* __restrict__ mC, const int* __restrict__ rowstart,
    const int* __restrict__ csr_src, const float* __restrict__ dinv,
    const float* __restrict__ bgc, unsigned short* __restrict__ hW2) {
    const int tid = threadIdx.x;
    const int d = blockIdx.x * 4 + (tid >> 6);
    const int t = tid & 63;
    float acc = bf2f(mC[(size_t)d * FOUT2 + t]);   // self loop
    int e = rowstart[d];
    const int eend = rowstart[d + 1];
    for (; e + 8 <= eend; e += 8) {
        const int s0 = csr_src[e],     s1 = csr_src[e + 1];
        const int s2 = csr_src[e + 2], s3 = csr_src[e + 3];
        const int s4 = csr_src[e + 4], s5 = csr_src[e + 5];
        const int s6 = csr_src[e + 6], s7 = csr_src[e + 7];
        const float v0 = bf2f(mC[(size_t)s0 * FOUT2 + t]);
        const float v1 = bf2f(mC[(size_t)s1 * FOUT2 + t]);
        const float v2 = bf2f(mC[(size_t)s2 * FOUT2 + t]);
        const float v3 = bf2f(mC[(size_t)s3 * FOUT2 + t]);
        const float v4 = bf2f(mC[(size_t)s4 * FOUT2 + t]);
        const float v5 = bf2f(mC[(size_t)s5 * FOUT2 + t]);
        const float v6 = bf2f(mC[(size_t)s6 * FOUT2 + t]);
        const float v7 = bf2f(mC[(size_t)s7 * FOUT2 + t]);
        acc += ((v0 + v1) + (v2 + v3)) + ((v4 + v5) + (v6 + v7));
    }
    for (; e < eend; ++e) acc += bf2f(mC[(size_t)csr_src[e] * FOUT2 + t]);
    hW2[(size_t)d * FOUT2 + t] = f2bf(acc * dinv[d] + bgc[t]);
}

// ---- ego apply (64-wide): Y2[yslot] = (A@A) @ hW2[ids] ---------------------
__global__ __launch_bounds__(256) void apply2_kernel(
    const unsigned short* __restrict__ hW2, const int* __restrict__ ego_ids,
    const float* __restrict__ ego_adj, const int* __restrict__ yslot,
    unsigned short* __restrict__ Y2) {
    __shared__ float Ar[8][KE * APAD];
    __shared__ float As[8][256];
    __shared__ int ids[8][KE];
    __shared__ int slots[8][KE];
    const int w = threadIdx.x >> 5;
    const int c = threadIdx.x & 31;
    const int n = blockIdx.x * 8 + w;
    const float* a = ego_adj + (size_t)n * 256;
#pragma unroll
    for (int e = 0; e < 8; ++e) {
        const int idx = c * 8 + e;
        Ar[w][(idx >> 4) * APAD + (idx & 15)] = a[idx];
    }
    if (c < KE) {
        ids[w][c] = ego_ids[n * KE + c];
        slots[w][c] = yslot[n * KE + c];
    }
    __syncthreads();
    {
        const int i = c >> 1;
        const int k0 = (c & 1) * 8;
        float s[8] = {};
#pragma unroll
        for (int j = 0; j < KE; ++j) {
            const float aij = Ar[w][i * APAD + j];
            const float* arow = &Ar[w][j * APAD + k0];
#pragma unroll
            for (int q = 0; q < 8; ++q) s[q] += aij * arow[q];
        }
        float4 s0 = {s[0], s[1], s[2], s[3]}, s1 = {s[4], s[5], s[6], s[7]};
        *(float4*)&As[w][i * 16 + k0]     = s0;
        *(float4*)&As[w][i * 16 + k0 + 4] = s1;
    }
    __syncthreads();
    float2 xg[KE];
#pragma unroll
    for (int k = 0; k < KE; ++k) xg[k] = ldu2(hW2, (size_t)ids[w][k] * FOUT2 + 2 * c);
#pragma unroll
    for (int i = 0; i < KE; ++i) {
        float sx = 0.f, sy = 0.f;
#pragma unroll
        for (int k = 0; k < KE; ++k) {
            const float a2 = As[w][i * 16 + k];
            sx += a2 * xg[k].x; sy += a2 * xg[k].y;
        }
        ushort2 o; o.x = f2bf(sx); o.y = f2bf(sy);
        *(ushort2*)(Y2 + (size_t)slots[w][i] * FOUT2 + 2 * c) = o;
    }
}

// ---- dual2 (matmul-free), wave-per-node, no shuffles, 8-deep ---------------
__global__ __launch_bounds__(256) void dual2_kernel(
    const unsigned short* __restrict__ Y2, const int* __restrict__ erowstart,
    const float* __restrict__ ndeg, const float* __restrict__ bc,
    const float* __restrict__ dinv, unsigned short* __restrict__ m2) {
    const int tid = threadIdx.x;
    const int d = blockIdx.x * 4 + (tid >> 6);
    const int t = tid & 63;
    float acc = 0.f;
    int s = erowstart[d];
    const int send = erowstart[d + 1];
    for (; s + 8 <= send; s += 8) {
        const float v0 = bf2f(Y2[(size_t)s * FOUT2 + t]);
        const float v1 = bf2f(Y2[(size_t)(s + 1) * FOUT2 + t]);
        const float v2 = bf2f(Y2[(size_t)(s + 2) * FOUT2 + t]);
        const float v3 = bf2f(Y2[(size_t)(s + 3) * FOUT2 + t]);
        const float v4 = bf2f(Y2[(size_t)(s + 4) * FOUT2 + t]);
        const float v5 = bf2f(Y2[(size_t)(s + 5) * FOUT2 + t]);
        const float v6 = bf2f(Y2[(size_t)(s + 6) * FOUT2 + t]);
        const float v7 = bf2f(Y2[(size_t)(s + 7) * FOUT2 + t]);
        acc += ((v0 + v1) + (v2 + v3)) + ((v4 + v5) + (v6 + v7));
    }
    for (; s < send; ++s) acc += bf2f(Y2[(size_t)s * FOUT2 + t]);
    m2[(size_t)d * FOUT2 + t] = f2bf((acc * ndeg[d] + bc[t]) * dinv[d]);
}

// ------- fused GCN gather (F=64) + bias + log_softmax -> fp32, 8-deep -------
__global__ __launch_bounds__(256) void gcn_gather_lsm_kernel(
    const unsigned short* __restrict__ msg, const int* __restrict__ rowstart,
    const int* __restrict__ csr_src, const float* __restrict__ dinv,
    const float* __restrict__ b, float* __restrict__ out) {
    const int tid = threadIdx.x;
    const int d = blockIdx.x * 4 + (tid >> 6);
    const int t = tid & 63;
    float s = bf2f(msg[(size_t)d * FOUT2 + t]);  // self loop
    int e = rowstart[d];
    const int eend = rowstart[d + 1];
    for (; e + 8 <= eend; e += 8) {
        const int s0 = csr_src[e],     s1 = csr_src[e + 1];
        const int s2 = csr_src[e + 2], s3 = csr_src[e + 3];
        const int s4 = csr_src[e + 4], s5 = csr_src[e + 5];
        const int s6 = csr_src[e + 6], s7 = csr_src[e + 7];
        const float v0 = bf2f(msg[(size_t)s0 * FOUT2 + t]);
        const float v1 = bf2f(msg[(size_t)s1 * FOUT2 + t]);
        const float v2 = bf2f(msg[(size_t)s2 * FOUT2 + t]);
        const float v3 = bf2f(msg[(size_t)s3 * FOUT2 + t]);
        const float v4 = bf2f(msg[(size_t)s4 * FOUT2 + t]);
        const float v5 = bf2f(msg[(size_t)s5 * FOUT2 + t]);
        const float v6 = bf2f(msg[(size_t)s6 * FOUT2 + t]);
        const float v7 = bf2f(msg[(size_t)s7 * FOUT2 + t]);
        s += ((v0 + v1) + (v2 + v3)) + ((v4 + v5) + (v6 + v7));
    }
    for (; e < eend; ++e) s += bf2f(msg[(size_t)csr_src[e] * FOUT2 + t]);
    const float xv = s * dinv[d] + b[t];
    float m = xv;
#pragma unroll
    for (int o = 32; o > 0; o >>= 1) m = fmaxf(m, __shfl_xor(m, o));
    float ex = __expf(xv - m);
    float sm = ex;
#pragma unroll
    for (int o = 32; o > 0; o >>= 1) sm += __shfl_xor(sm, o);
    out[(size_t)d * FOUT2 + t] = xv - m - __logf(sm);
}

extern "C" void kernel_launch(void* const* d_in, const int* in_sizes, int n_in,
                              void* d_out, int out_size, void* d_ws, size_t ws_size,
                              hipStream_t stream) {
    (void)in_sizes; (void)n_in; (void)out_size; (void)ws_size;
    const float* x      = (const float*)d_in[0];
    const int*   eidx   = (const int*)d_in[1];
    const int*   egoids = (const int*)d_in[2];
    const float* egoadj = (const float*)d_in[3];
    const float* ndeg   = (const float*)d_in[4];
    const float* W_ego1 = (const float*)d_in[5];
    const float* b_ego1 = (const float*)d_in[6];
    const float* W_gcn1 = (const float*)d_in[7];
    const float* b_gcn1 = (const float*)d_in[8];
    const float* W_ego2 = (const float*)d_in[9];
    const float* b_ego2 = (const float*)d_in[10];
    const float* W_gcn2 = (const float*)d_in[11];
    const float* b_gcn2 = (const float*)d_in[12];
    const int* src = eidx;
    const int* dst = eidx + NE;

    // ---- workspace layout ----
    int* ip = (int*)d_ws;
    int* rowstart  = ip;                    // NN+1 (+pad)
    int* erowstart = rowstart + NN + 8;     // NN+1 (+pad)
    int* csr_src   = erowstart + NN + 8;    // NE
    int* yslot     = csr_src + NE;          // NN*KE
    int* scantmp   = yslot + NN * KE;       // 2*NN
    int* bsums     = scantmp + 2 * NN;      // 2*NB (+pad)
    unsigned short* counts_e = (unsigned short*)(bsums + 256);  // BE*NN u16
    unsigned short* counts_g = counts_e + BE * NN;              // BG*NN u16
    unsigned short* posarr   = counts_g + BG * NN;              // TOT u16
    float* dinv = (float*)(posarr + TOT);               // NN
    float* Wc   = dinv + NN;                            // 128*64 fp32 (stage 1)
    float* Wgc  = Wc + FIN * FOUT2;                     // 128*64 fp32 (stage 2)
    float* bc   = Wgc + FIN * FOUT2;                    // 64
    float* bgc  = bc + 64;                              // 64
    unsigned short* xW1 = (unsigned short*)(bgc + 64);   // NN*128 bf16
    unsigned short* mC  = xW1 + (size_t)NN * FIN;        // NN*64 bf16 (GCN-1 msg, Wc-folded)
    unsigned short* hW2 = mC + (size_t)NN * FOUT2;       // NN*64  bf16
    unsigned short* m2  = hW2 + (size_t)NN * FOUT2;      // NN*64  bf16 msgs L2
    unsigned short* Y   = m2 + (size_t)NN * FOUT2;       // NN*KE*128 bf16 (CSR order)

    // ---- CSR build (LDS hist) || xW1 GEMM || Wc = We2@Wg2 ----
    mega_kernel<<<BE + BG + GB1 + 33, 256, 0, stream>>>(dst, egoids,
                                                        counts_e, counts_g, posarr,
                                                        x, W_ego1, xW1,
                                                        W_ego2, W_gcn2, b_ego2, Wc, bc);
    // ---- plane scan || Wgc = Wg1@Wc ----
    scan_p1_kernel<<<2 * NB + 33, 256, 0, stream>>>(counts_e, counts_g, scantmp,
                                                    bsums, dinv,
                                                    W_gcn1, b_gcn1, Wc, Wgc, bgc);
    // ---- bucket (scan_p3 folded in) ----
    bucket3_kernel<<<HB, 256, 0, stream>>>(src, dst, egoids, scantmp, bsums,
                                           counts_e, counts_g, posarr,
                                           csr_src, yslot, rowstart, erowstart);

    // ---- layer 1 ----
    ego_apply_kernel<<<NN / 8, 256, 0, stream>>>(xW1, egoids, egoadj, yslot, Y);
    dual1_kernel<<<NN / 8, 256, 0, stream>>>(Y, erowstart, ndeg, b_ego1, Wgc, dinv, mC);
    gcn2_gather64_kernel<<<NN / 4, 256, 0, stream>>>(mC, rowstart, csr_src, dinv, bgc, hW2);

    // ---- layer 2 (weights pre-combined; ego runs on 64-wide hW2) ----
    apply2_kernel<<<NN / 8, 256, 0, stream>>>(hW2, egoids, egoadj, yslot, Y);
    dual2_kernel<<<NN / 4, 256, 0, stream>>>(Y, erowstart, ndeg, bc, dinv, m2);
    gcn_gather_lsm_kernel<<<NN / 4, 256, 0, stream>>>(m2, rowstart, csr_src, dinv, b_gcn2, (float*)d_out);
}